// Round 10
// baseline (252.655 us; speedup 1.0000x reference)
//
#include <hip/hip_runtime.h>
#include <hip/hip_bf16.h>
#include <stdint.h>

// B=2, T=4096, D=1024, H=16, HS=64. Pipeline:
// fused cvt -> GEMM qkv (V written TRANSPOSED [bh][e][t]) -> flash attn
// (32x32 MFMA swapped QK^T, in-reg softmax, cvt_pk+permlane32_swap, defer-
// rescale, dbuf swizzled K/V, uniform-work paired grid) -> GEMM out.

typedef __bf16 bf16x8 __attribute__((ext_vector_type(8)));
typedef float f32x4 __attribute__((ext_vector_type(4)));
typedef float f32x16 __attribute__((ext_vector_type(16)));
typedef __attribute__((address_space(1))) void gvoid_t;
typedef __attribute__((address_space(3))) void lvoid_t;

using hbf = __hip_bfloat16;

#define QSCALE (0.125f * 1.44269504088896f)  // 1/sqrt(HS) * log2(e)

static __device__ __forceinline__ void gload_lds16(const void* g, void* l) {
  __builtin_amdgcn_global_load_lds((gvoid_t*)g, (lvoid_t*)l, 16, 0, 0);
}

static __device__ __forceinline__ uint16_t b2u(float x) {
  hbf h = __float2bfloat16(x);
  return *reinterpret_cast<uint16_t*>(&h);
}

static __device__ __forceinline__ uint32_t cvtpk(float lo, float hi) {
  uint32_t r;
  asm("v_cvt_pk_bf16_f32 %0, %1, %2" : "=v"(r) : "v"(lo), "v"(hi));
  return r;
}

// v_permlane32_swap_b32: newX = {X.lo31 | Y.lo31->hi}, newY = {X.hi31->lo | Y.hi31}
static __device__ __forceinline__ void pl32swap(uint32_t& x, uint32_t& y) {
  asm volatile("v_permlane32_swap_b32 %0, %1" : "+v"(x), "+v"(y));
}

// ---------------- fused converters ----------------
// blocks [0,8192): x->xb ; [8192,20480): Wqkv->Wt ; [20480,24576): Wp->Wpt ;
// [24576,24588): biases -> biasc.

__global__ void k_cvt_all(const float* __restrict__ x,
                          const float* __restrict__ Wq, const float* __restrict__ Wk,
                          const float* __restrict__ Wv,
                          const float* __restrict__ bq, const float* __restrict__ bk,
                          const float* __restrict__ bv,
                          const float* __restrict__ Wp,
                          hbf* __restrict__ xb, hbf* __restrict__ Wt,
                          hbf* __restrict__ Wpt, float* __restrict__ biasc) {
  const int b = blockIdx.x, tid = threadIdx.x;
  if (b < 8192) {
    int i = (b * 256 + tid) * 4;
    float4 v = *reinterpret_cast<const float4*>(x + i);
    hbf h[4] = {__float2bfloat16(v.x), __float2bfloat16(v.y),
                __float2bfloat16(v.z), __float2bfloat16(v.w)};
    *reinterpret_cast<ushort4*>(xb + i) = *reinterpret_cast<ushort4*>(h);
  } else if (b < 20480) {
    int idx = (b - 8192) * 256 + tid;   // 3072*1024
    int d = idx & 1023, r = idx >> 10;
    int m = r >> 10, rem = r & 1023;
    int h = rem >> 6, e = rem & 63;
    const float* W = (m == 0) ? Wq : (m == 1) ? Wk : Wv;
    float v = W[(h << 10 | d) * 64 + e];
    if (m == 0) v *= QSCALE;
    Wt[idx] = __float2bfloat16(v);
  } else if (b < 24576) {
    int idx = (b - 20480) * 256 + tid;  // 1024*1024
    int o = idx >> 10, d = idx & 1023;
    Wpt[idx] = __float2bfloat16(Wp[(d << 10) + o]);
  } else {
    int r = (b - 24576) * 256 + tid;    // 0..3071
    int m = r >> 10, rem = r & 1023;
    const float* bsrc = (m == 0) ? bq : (m == 1) ? bk : bv;
    float v = bsrc[rem];
    if (m == 0) v *= QSCALE;
    biasc[r] = v;
  }
}

// ---------------- QKV projection GEMM ----------------
// Q,K -> qkv[mi][bh][t][e] ; V -> transposed [bh][e][t] (packed 8B stores).

__global__ __launch_bounds__(256) void k_gemm_qkv(
    const hbf* __restrict__ A, const hbf* __restrict__ Bw,
    const float* __restrict__ biasc, hbf* __restrict__ qkv) {
  __shared__ __align__(16) hbf sA[128 * 64];
  __shared__ __align__(16) hbf sB[128 * 64];
  const int tid = threadIdx.x;
  const int lane = tid & 63, wid = tid >> 6;
  const int m0 = blockIdx.x * 128, n0 = blockIdx.y * 128;
  const int g = lane >> 4, cl = lane & 15;

  const f32x4 fz = {0.f, 0.f, 0.f, 0.f};
  f32x4 acc[4][4];
#pragma unroll
  for (int a = 0; a < 4; ++a)
#pragma unroll
    for (int b = 0; b < 4; ++b) acc[a][b] = fz;

  const int srow = wid * 32 + (lane >> 3);
  const int scol = (lane & 7) * 8;

  for (int kt = 0; kt < 16; ++kt) {
    const int k0 = kt * 64;
#pragma unroll
    for (int t = 0; t < 4; ++t) {
      const int r = srow + t * 8;
      gload_lds16(A + (size_t)(m0 + r) * 1024 + k0 + scol, sA + (wid * 32 + t * 8) * 64);
      gload_lds16(Bw + (size_t)(n0 + r) * 1024 + k0 + scol, sB + (wid * 32 + t * 8) * 64);
    }
    __syncthreads();
#pragma unroll
    for (int ks = 0; ks < 2; ++ks) {
      const int ko = ks * 32 + g * 8;
      bf16x8 af[4], bfr[4];
#pragma unroll
      for (int rt = 0; rt < 4; ++rt)
        af[rt] = *reinterpret_cast<const bf16x8*>(sA + ((wid & 1) * 64 + rt * 16 + cl) * 64 + ko);
#pragma unroll
      for (int ct = 0; ct < 4; ++ct)
        bfr[ct] = *reinterpret_cast<const bf16x8*>(sB + ((wid >> 1) * 64 + ct * 16 + cl) * 64 + ko);
#pragma unroll
      for (int rt = 0; rt < 4; ++rt)
#pragma unroll
        for (int ct = 0; ct < 4; ++ct)
          acc[rt][ct] = __builtin_amdgcn_mfma_f32_16x16x32_bf16(af[rt], bfr[ct], acc[rt][ct], 0, 0, 0);
    }
    __syncthreads();
  }

#pragma unroll
  for (int rt = 0; rt < 4; ++rt)
#pragma unroll
    for (int ct = 0; ct < 4; ++ct) {
      const int colg = n0 + (wid >> 1) * 64 + ct * 16 + cl;
      const int mi = colg >> 10, rem = colg & 1023;
      const int h = rem >> 6, e = rem & 63;
      const float bi = biasc[colg];
      if (mi == 2) {
        const int t0 = m0 + (wid & 1) * 64 + rt * 16 + g * 4;
        const int b = t0 >> 12, t = t0 & 4095;
        ushort4 o;
        o.x = b2u(acc[rt][ct][0] + bi);
        o.y = b2u(acc[rt][ct][1] + bi);
        o.z = b2u(acc[rt][ct][2] + bi);
        o.w = b2u(acc[rt][ct][3] + bi);
        *reinterpret_cast<ushort4*>(
            qkv + (size_t)64 * 262144 + (size_t)(b * 16 + h) * 262144 + (size_t)e * 4096 + t) = o;
      } else {
#pragma unroll
        for (int i = 0; i < 4; ++i) {
          const int rowg = m0 + (wid & 1) * 64 + rt * 16 + g * 4 + i;
          const int b = rowg >> 12, t = rowg & 4095;
          qkv[(((size_t)mi * 32 + b * 16 + h) * 4096 + t) * 64 + e] =
              __float2bfloat16(acc[rt][ct][i] + bi);
        }
      }
    }
}

// ---------------- flash attention ----------------
// grid (bh=32, 16). Block y runs q-tile qtb=31-y then qtb=y: (2(31-y)+2) +
// (2y+2) = 66 tile-iters for EVERY block -> uniform work, no tail.
// Per q-tile: 4 waves x 32 q-rows, 32x32x16 MFMA swapped (S^T = mfma(K,Q)),
// lane owns q-col l&31; in-reg softmax + shfl_xor(32); defer-rescale THR=8;
// P->bf16 cvt_pk + permlane32_swap into PV B-frag (no DS); PV=mfma(V^T,P^T).
// K, V^T staged via XOR-swizzled global_load_lds; dbuf, one barrier/iter.

__global__ __launch_bounds__(256) void k_flash(
    const hbf* __restrict__ qkv, hbf* __restrict__ attn) {
  __shared__ __align__(16) __bf16 sK[2][64 * 64];
  __shared__ __align__(16) __bf16 sV[2][64 * 64];
  const int tid = threadIdx.x, lane = tid & 63, wq = tid >> 6;
  const int h = lane >> 5, r31 = lane & 31;
  const int bh = blockIdx.x;
  const hbf* Q  = qkv + (size_t)bh * 262144;
  const hbf* Kp = qkv + (size_t)(32 + bh) * 262144;
  const hbf* Vp = qkv + (size_t)(64 + bh) * 262144;  // [e=64][t=4096]
  const float NEG_INF = -__builtin_inff();

  const int koff = (wq * 16 + (lane >> 3)) * 64 + (((lane & 7) ^ (lane >> 3)) * 8);
  const int voff = (wq * 16 + (lane >> 3)) * 4096 + (((lane & 7) ^ (lane >> 3)) * 8);

  auto run = [&](int qtb) {
    const int q0 = qtb * 128;
    const int ntile = 2 * qtb + 2;
    const int qrow = q0 + wq * 32 + r31;

    bf16x8 aq[4];
#pragma unroll
    for (int ks = 0; ks < 4; ++ks)
      aq[ks] = *reinterpret_cast<const bf16x8*>(Q + (size_t)qrow * 64 + ks * 16 + h * 8);

    f32x16 accO[2];
#pragma unroll
    for (int et = 0; et < 2; ++et)
#pragma unroll
      for (int i = 0; i < 16; ++i) accO[et][i] = 0.f;
    float mrow = NEG_INF, lrow = 0.f;

    // prologue: stage tile 0 into buf 0 (safe: prior loop ended on a barrier)
    gload_lds16(Kp + koff,         &sK[0][wq * 1024]);
    gload_lds16(Kp + koff + 512,   &sK[0][wq * 1024 + 512]);
    gload_lds16(Vp + voff,         &sV[0][wq * 1024]);
    gload_lds16(Vp + voff + 32768, &sV[0][wq * 1024 + 512]);
    __syncthreads();

    const int qmaxw = q0 + wq * 32 + 31;
    int buf = 0;
    for (int jt = 0; jt < ntile; ++jt) {
      if (jt < ntile - 1) {  // prefetch next tile (pure DMA)
        const hbf* Kg = Kp + (size_t)(jt + 1) * 4096;
        gload_lds16(Kg + koff,       &sK[buf ^ 1][wq * 1024]);
        gload_lds16(Kg + koff + 512, &sK[buf ^ 1][wq * 1024 + 512]);
        const hbf* Vg = Vp + (jt + 1) * 64;
        gload_lds16(Vg + voff,         &sV[buf ^ 1][wq * 1024]);
        gload_lds16(Vg + voff + 32768, &sV[buf ^ 1][wq * 1024 + 512]);
      }

      if (64 * jt <= qmaxw) {  // wave has unmasked work in this tile
        const __bf16* sKb = sK[buf];
        const __bf16* sVb = sV[buf];

        f32x16 accS[2];
        __builtin_amdgcn_s_setprio(1);
#pragma unroll
        for (int t = 0; t < 2; ++t) {
          f32x16 s;
#pragma unroll
          for (int i = 0; i < 16; ++i) s[i] = 0.f;
#pragma unroll
          for (int ks = 0; ks < 4; ++ks) {
            bf16x8 ak = *reinterpret_cast<const bf16x8*>(
                sKb + (t * 32 + r31) * 64 + (((2 * ks + h) ^ (r31 & 7)) * 8));
            s = __builtin_amdgcn_mfma_f32_32x32x16_bf16(ak, aq[ks], s, 0, 0, 0);
          }
          accS[t] = s;
        }
        __builtin_amdgcn_s_setprio(0);

        if (64 * jt + 63 > q0 + wq * 32) {  // diagonal region: mask kv > q
#pragma unroll
          for (int t = 0; t < 2; ++t)
#pragma unroll
            for (int i = 0; i < 16; ++i) {
              const int kvg = 64 * jt + 32 * t + (i & 3) + 8 * (i >> 2) + 4 * h;
              if (kvg > qrow) accS[t][i] = NEG_INF;
            }
        }

        float a0 = fmaxf(fmaxf(accS[0][0], accS[0][1]), fmaxf(accS[0][2], accS[0][3]));
        float a1 = fmaxf(fmaxf(accS[0][4], accS[0][5]), fmaxf(accS[0][6], accS[0][7]));
        float a2 = fmaxf(fmaxf(accS[0][8], accS[0][9]), fmaxf(accS[0][10], accS[0][11]));
        float a3 = fmaxf(fmaxf(accS[0][12], accS[0][13]), fmaxf(accS[0][14], accS[0][15]));
        float a4 = fmaxf(fmaxf(accS[1][0], accS[1][1]), fmaxf(accS[1][2], accS[1][3]));
        float a5 = fmaxf(fmaxf(accS[1][4], accS[1][5]), fmaxf(accS[1][6], accS[1][7]));
        float a6 = fmaxf(fmaxf(accS[1][8], accS[1][9]), fmaxf(accS[1][10], accS[1][11]));
        float a7 = fmaxf(fmaxf(accS[1][12], accS[1][13]), fmaxf(accS[1][14], accS[1][15]));
        float pmax = fmaxf(fmaxf(fmaxf(a0, a1), fmaxf(a2, a3)),
                           fmaxf(fmaxf(a4, a5), fmaxf(a6, a7)));
        pmax = fmaxf(pmax, __shfl_xor(pmax, 32));

        if (!__all(pmax - mrow <= 8.f)) {  // defer-rescale (T13)
          const float mn = fmaxf(mrow, pmax);
          const float corr = __builtin_amdgcn_exp2f(mrow - mn);
          mrow = mn;
          lrow *= corr;
#pragma unroll
          for (int et = 0; et < 2; ++et)
#pragma unroll
            for (int i = 0; i < 16; ++i) accO[et][i] *= corr;
        }

#pragma unroll
        for (int t = 0; t < 2; ++t)
#pragma unroll
          for (int i = 0; i < 16; ++i)
            accS[t][i] = __builtin_amdgcn_exp2f(accS[t][i] - mrow);
        float s0 = (accS[0][0] + accS[0][1]) + (accS[0][2] + accS[0][3]);
        float s1 = (accS[0][4] + accS[0][5]) + (accS[0][6] + accS[0][7]);
        float s2 = (accS[0][8] + accS[0][9]) + (accS[0][10] + accS[0][11]);
        float s3 = (accS[0][12] + accS[0][13]) + (accS[0][14] + accS[0][15]);
        float s4 = (accS[1][0] + accS[1][1]) + (accS[1][2] + accS[1][3]);
        float s5 = (accS[1][4] + accS[1][5]) + (accS[1][6] + accS[1][7]);
        float s6 = (accS[1][8] + accS[1][9]) + (accS[1][10] + accS[1][11]);
        float s7 = (accS[1][12] + accS[1][13]) + (accS[1][14] + accS[1][15]);
        float rs = ((s0 + s1) + (s2 + s3)) + ((s4 + s5) + (s6 + s7));
        rs += __shfl_xor(rs, 32);
        lrow += rs;

        uint32_t d0[2][4], d1[2][4];
#pragma unroll
        for (int t = 0; t < 2; ++t)
#pragma unroll
          for (int r4 = 0; r4 < 4; ++r4) {
            d0[t][r4] = cvtpk(accS[t][4 * r4 + 0], accS[t][4 * r4 + 1]);
            d1[t][r4] = cvtpk(accS[t][4 * r4 + 2], accS[t][4 * r4 + 3]);
          }

        // u[0] = newX of swap(d[ra], d[rb]) ; u[2] = newY (derived, R9-verified)
#pragma unroll
        for (int kb = 0; kb < 4; ++kb) {
          const int t = kb >> 1, ra = 2 * (kb & 1), rb = ra + 1;
          uint32_t x0 = d0[t][ra], y0 = d0[t][rb];
          uint32_t x1 = d1[t][ra], y1 = d1[t][rb];
          pl32swap(x0, y0);
          pl32swap(x1, y1);
          union { uint32_t u[4]; bf16x8 v; } bP;
          bP.u[0] = x0; bP.u[1] = x1; bP.u[2] = y0; bP.u[3] = y1;
          __builtin_amdgcn_s_setprio(1);
#pragma unroll
          for (int et = 0; et < 2; ++et) {
            bf16x8 av = *reinterpret_cast<const bf16x8*>(
                sVb + (et * 32 + r31) * 64 + (((2 * kb + h) ^ (r31 & 7)) * 8));
            accO[et] = __builtin_amdgcn_mfma_f32_32x32x16_bf16(av, bP.v, accO[et], 0, 0, 0);
          }
          __builtin_amdgcn_s_setprio(0);
        }
      }

      __syncthreads();  // drains K/V DMA; all waves done with buf
      buf ^= 1;
    }

    // epilogue: accO[et][i] = O^T[e=(i&3)+8*(i>>2)+4h+32et][q=r31]
    const float inv = 1.0f / lrow;
    hbf* arow = attn + ((size_t)(bh >> 4) * 4096 + qrow) * 1024 + (bh & 15) * 64;
#pragma unroll
    for (int et = 0; et < 2; ++et)
#pragma unroll
      for (int r4 = 0; r4 < 4; ++r4) {
        const int e0 = et * 32 + 8 * r4 + 4 * h;
        ushort4 o;
        o.x = b2u(accO[et][4 * r4 + 0] * inv);
        o.y = b2u(accO[et][4 * r4 + 1] * inv);
        o.z = b2u(accO[et][4 * r4 + 2] * inv);
        o.w = b2u(accO[et][4 * r4 + 3] * inv);
        *reinterpret_cast<ushort4*>(arow + e0) = o;
      }
  };

  run(31 - (int)blockIdx.y);  // big half of the pair first
  run((int)blockIdx.y);       // small half; total 66 tile-iters per block
}

// ---------------- output projection GEMM ----------------

__global__ __launch_bounds__(256) void k_gemm_out(
    const hbf* __restrict__ A, const hbf* __restrict__ Bw,
    const float* __restrict__ bp, float* __restrict__ out) {
  __shared__ __align__(16) hbf sA[128 * 64];
  __shared__ __align__(16) hbf sB[128 * 64];
  const int tid = threadIdx.x;
  const int lane = tid & 63, wid = tid >> 6;
  const int m0 = blockIdx.x * 128, n0 = blockIdx.y * 128;
  const int g = lane >> 4, cl = lane & 15;

  const f32x4 fz = {0.f, 0.f, 0.f, 0.f};
  f32x4 acc[4][4];
#pragma unroll
  for (int a = 0; a < 4; ++a)
#pragma unroll
    for (int b = 0; b < 4; ++b) acc[a][b] = fz;

  const int srow = wid * 32 + (lane >> 3);
  const int scol = (lane & 7) * 8;

  for (int kt = 0; kt < 16; ++kt) {
    const int k0 = kt * 64;
#pragma unroll
    for (int t = 0; t < 4; ++t) {
      const int r = srow + t * 8;
      gload_lds16(A + (size_t)(m0 + r) * 1024 + k0 + scol, sA + (wid * 32 + t * 8) * 64);
      gload_lds16(Bw + (size_t)(n0 + r) * 1024 + k0 + scol, sB + (wid * 32 + t * 8) * 64);
    }
    __syncthreads();
#pragma unroll
    for (int ks = 0; ks < 2; ++ks) {
      const int ko = ks * 32 + g * 8;
      bf16x8 af[4], bfr[4];
#pragma unroll
      for (int rt = 0; rt < 4; ++rt)
        af[rt] = *reinterpret_cast<const bf16x8*>(sA + ((wid & 1) * 64 + rt * 16 + cl) * 64 + ko);
#pragma unroll
      for (int ct = 0; ct < 4; ++ct)
        bfr[ct] = *reinterpret_cast<const bf16x8*>(sB + ((wid >> 1) * 64 + ct * 16 + cl) * 64 + ko);
#pragma unroll
      for (int rt = 0; rt < 4; ++rt)
#pragma unroll
        for (int ct = 0; ct < 4; ++ct)
          acc[rt][ct] = __builtin_amdgcn_mfma_f32_16x16x32_bf16(af[rt], bfr[ct], acc[rt][ct], 0, 0, 0);
    }
    __syncthreads();
  }

#pragma unroll
  for (int rt = 0; rt < 4; ++rt)
#pragma unroll
    for (int ct = 0; ct < 4; ++ct) {
      const int colg = n0 + (wid >> 1) * 64 + ct * 16 + cl;
      const float bi = bp[colg];
#pragma unroll
      for (int i = 0; i < 4; ++i) {
        const int rowg = m0 + (wid & 1) * 64 + rt * 16 + g * 4 + i;
        out[(size_t)rowg * 1024 + colg] = acc[rt][ct][i] + bi;
      }
    }
}

// ---------------- launcher ----------------

extern "C" void kernel_launch(void* const* d_in, const int* in_sizes, int n_in,
                              void* d_out, int out_size, void* d_ws, size_t ws_size,
                              hipStream_t stream) {
  const float* x  = (const float*)d_in[0];
  const float* Wq = (const float*)d_in[1];
  const float* Wk = (const float*)d_in[2];
  const float* Wv = (const float*)d_in[3];
  const float* bq = (const float*)d_in[4];
  const float* bk = (const float*)d_in[5];
  const float* bv = (const float*)d_in[6];
  const float* Wp = (const float*)d_in[7];
  const float* bp = (const float*)d_in[8];
  float* out = (float*)d_out;

  char* ws = (char*)d_ws;
  hbf*   xb    = (hbf*)ws;                                   // 16 MiB (reused as attn_out)
  hbf*   Wt    = (hbf*)(ws + 16777216);                      // 6 MiB
  hbf*   Wpt   = (hbf*)(ws + 16777216 + 6291456);            // 2 MiB
  float* biasc = (float*)(ws + 16777216 + 6291456 + 2097152);// 12 KiB (+pad)
  hbf*   qkv   = (hbf*)(ws + 16777216 + 6291456 + 2097152 + 16384); // 48 MiB
  hbf*   attn  = xb;

  k_cvt_all<<<24588, 256, 0, stream>>>(x, Wq, Wk, Wv, bq, bk, bv, Wp,
                                       xb, Wt, Wpt, biasc);

  dim3 g1(64, 24); k_gemm_qkv<<<g1, 256, 0, stream>>>(xb, Wt, biasc, qkv);
  dim3 g2(32, 16); k_flash   <<<g2, 256, 0, stream>>>(qkv, attn);
  dim3 g3(64, 8);  k_gemm_out<<<g3, 256, 0, stream>>>(attn, Wpt, bp, out);
}

// Round 11
// 244.422 us; speedup vs baseline: 1.0337x; 1.0337x over previous
//
#include <hip/hip_runtime.h>
#include <hip/hip_bf16.h>
#include <stdint.h>

// B=2, T=4096, D=1024, H=16, HS=64. Pipeline:
// fused cvt -> GEMM qkv (XCD-swizzled; V written TRANSPOSED [bh][e][t]) ->
// flash attn (R9 topology: grid 32x32 descending qt; 32x32 MFMA swapped QK^T,
// in-reg softmax w/ max3 tree, cvt_pk+permlane32_swap, defer-rescale, dbuf
// swizzled K/V) -> GEMM out (XCD-swizzled).

typedef __bf16 bf16x8 __attribute__((ext_vector_type(8)));
typedef float f32x4 __attribute__((ext_vector_type(4)));
typedef float f32x16 __attribute__((ext_vector_type(16)));
typedef __attribute__((address_space(1))) void gvoid_t;
typedef __attribute__((address_space(3))) void lvoid_t;

using hbf = __hip_bfloat16;

#define QSCALE (0.125f * 1.44269504088896f)  // 1/sqrt(HS) * log2(e)

static __device__ __forceinline__ void gload_lds16(const void* g, void* l) {
  __builtin_amdgcn_global_load_lds((gvoid_t*)g, (lvoid_t*)l, 16, 0, 0);
}

static __device__ __forceinline__ uint16_t b2u(float x) {
  hbf h = __float2bfloat16(x);
  return *reinterpret_cast<uint16_t*>(&h);
}

static __device__ __forceinline__ uint32_t cvtpk(float lo, float hi) {
  uint32_t r;
  asm("v_cvt_pk_bf16_f32 %0, %1, %2" : "=v"(r) : "v"(lo), "v"(hi));
  return r;
}

// v_permlane32_swap_b32: newX = {X.lo31 | Y.lo31->hi}, newY = {X.hi31->lo | Y.hi31}
static __device__ __forceinline__ void pl32swap(uint32_t& x, uint32_t& y) {
  asm volatile("v_permlane32_swap_b32 %0, %1" : "+v"(x), "+v"(y));
}

static __device__ __forceinline__ float max3f(float a, float b, float c) {
  return fmaxf(fmaxf(a, b), c);  // fuses to v_max3_f32
}

// ---------------- fused converters ----------------
// blocks [0,8192): x->xb ; [8192,20480): Wqkv->Wt ; [20480,24576): Wp->Wpt ;
// [24576,24588): biases -> biasc.

__global__ void k_cvt_all(const float* __restrict__ x,
                          const float* __restrict__ Wq, const float* __restrict__ Wk,
                          const float* __restrict__ Wv,
                          const float* __restrict__ bq, const float* __restrict__ bk,
                          const float* __restrict__ bv,
                          const float* __restrict__ Wp,
                          hbf* __restrict__ xb, hbf* __restrict__ Wt,
                          hbf* __restrict__ Wpt, float* __restrict__ biasc) {
  const int b = blockIdx.x, tid = threadIdx.x;
  if (b < 8192) {
    int i = (b * 256 + tid) * 4;
    float4 v = *reinterpret_cast<const float4*>(x + i);
    hbf h[4] = {__float2bfloat16(v.x), __float2bfloat16(v.y),
                __float2bfloat16(v.z), __float2bfloat16(v.w)};
    *reinterpret_cast<ushort4*>(xb + i) = *reinterpret_cast<ushort4*>(h);
  } else if (b < 20480) {
    int idx = (b - 8192) * 256 + tid;   // 3072*1024
    int d = idx & 1023, r = idx >> 10;
    int m = r >> 10, rem = r & 1023;
    int h = rem >> 6, e = rem & 63;
    const float* W = (m == 0) ? Wq : (m == 1) ? Wk : Wv;
    float v = W[(h << 10 | d) * 64 + e];
    if (m == 0) v *= QSCALE;
    Wt[idx] = __float2bfloat16(v);
  } else if (b < 24576) {
    int idx = (b - 20480) * 256 + tid;  // 1024*1024
    int o = idx >> 10, d = idx & 1023;
    Wpt[idx] = __float2bfloat16(Wp[(d << 10) + o]);
  } else {
    int r = (b - 24576) * 256 + tid;    // 0..3071
    int m = r >> 10, rem = r & 1023;
    const float* bsrc = (m == 0) ? bq : (m == 1) ? bk : bv;
    float v = bsrc[rem];
    if (m == 0) v *= QSCALE;
    biasc[r] = v;
  }
}

// ---------------- QKV projection GEMM ----------------
// Q,K -> qkv[mi][bh][t][e] ; V -> transposed [bh][e][t] (packed 8B stores).
// XCD-chunked block swizzle (1536 wgs, 192/XCD): co-resident blocks share a
// B-panel -> L2-resident Wt panel per XCD.

__global__ __launch_bounds__(256) void k_gemm_qkv(
    const hbf* __restrict__ A, const hbf* __restrict__ Bw,
    const float* __restrict__ biasc, hbf* __restrict__ qkv) {
  __shared__ __align__(16) hbf sA[128 * 64];
  __shared__ __align__(16) hbf sB[128 * 64];
  const int tid = threadIdx.x;
  const int lane = tid & 63, wid = tid >> 6;
  int wg = blockIdx.y * 64 + blockIdx.x;       // 0..1535
  wg = (wg & 7) * 192 + (wg >> 3);             // bijective XCD chunking
  const int m0 = (wg & 63) * 128, n0 = (wg >> 6) * 128;
  const int g = lane >> 4, cl = lane & 15;

  const f32x4 fz = {0.f, 0.f, 0.f, 0.f};
  f32x4 acc[4][4];
#pragma unroll
  for (int a = 0; a < 4; ++a)
#pragma unroll
    for (int b = 0; b < 4; ++b) acc[a][b] = fz;

  const int srow = wid * 32 + (lane >> 3);
  const int scol = (lane & 7) * 8;

  for (int kt = 0; kt < 16; ++kt) {
    const int k0 = kt * 64;
#pragma unroll
    for (int t = 0; t < 4; ++t) {
      const int r = srow + t * 8;
      gload_lds16(A + (size_t)(m0 + r) * 1024 + k0 + scol, sA + (wid * 32 + t * 8) * 64);
      gload_lds16(Bw + (size_t)(n0 + r) * 1024 + k0 + scol, sB + (wid * 32 + t * 8) * 64);
    }
    __syncthreads();
#pragma unroll
    for (int ks = 0; ks < 2; ++ks) {
      const int ko = ks * 32 + g * 8;
      bf16x8 af[4], bfr[4];
#pragma unroll
      for (int rt = 0; rt < 4; ++rt)
        af[rt] = *reinterpret_cast<const bf16x8*>(sA + ((wid & 1) * 64 + rt * 16 + cl) * 64 + ko);
#pragma unroll
      for (int ct = 0; ct < 4; ++ct)
        bfr[ct] = *reinterpret_cast<const bf16x8*>(sB + ((wid >> 1) * 64 + ct * 16 + cl) * 64 + ko);
#pragma unroll
      for (int rt = 0; rt < 4; ++rt)
#pragma unroll
        for (int ct = 0; ct < 4; ++ct)
          acc[rt][ct] = __builtin_amdgcn_mfma_f32_16x16x32_bf16(af[rt], bfr[ct], acc[rt][ct], 0, 0, 0);
    }
    __syncthreads();
  }

#pragma unroll
  for (int rt = 0; rt < 4; ++rt)
#pragma unroll
    for (int ct = 0; ct < 4; ++ct) {
      const int colg = n0 + (wid >> 1) * 64 + ct * 16 + cl;
      const int mi = colg >> 10, rem = colg & 1023;
      const int h = rem >> 6, e = rem & 63;
      const float bi = biasc[colg];
      if (mi == 2) {
        const int t0 = m0 + (wid & 1) * 64 + rt * 16 + g * 4;
        const int b = t0 >> 12, t = t0 & 4095;
        ushort4 o;
        o.x = b2u(acc[rt][ct][0] + bi);
        o.y = b2u(acc[rt][ct][1] + bi);
        o.z = b2u(acc[rt][ct][2] + bi);
        o.w = b2u(acc[rt][ct][3] + bi);
        *reinterpret_cast<ushort4*>(
            qkv + (size_t)64 * 262144 + (size_t)(b * 16 + h) * 262144 + (size_t)e * 4096 + t) = o;
      } else {
#pragma unroll
        for (int i = 0; i < 4; ++i) {
          const int rowg = m0 + (wid & 1) * 64 + rt * 16 + g * 4 + i;
          const int b = rowg >> 12, t = rowg & 4095;
          qkv[(((size_t)mi * 32 + b * 16 + h) * 4096 + t) * 64 + e] =
              __float2bfloat16(acc[rt][ct][i] + bi);
        }
      }
    }
}

// ---------------- flash attention ----------------
// grid (bh=32, 32); qtb = 31 - blockIdx.y (big first, LPT-style). Q-tile 128:
// 4 waves x 32 q-rows. 32x32x16 MFMA swapped (S^T = mfma(K,Q)); lane owns
// q-col l&31; in-reg softmax (max3 tree) + shfl_xor(32); defer-rescale THR=8;
// P->bf16 cvt_pk + permlane32_swap into PV B-frag (no DS); PV=mfma(V^T,P^T).
// K, V^T staged via XOR-swizzled global_load_lds; dbuf, one barrier/iter.

__global__ __launch_bounds__(256) void k_flash(
    const hbf* __restrict__ qkv, hbf* __restrict__ attn) {
  __shared__ __align__(16) __bf16 sK[2][64 * 64];
  __shared__ __align__(16) __bf16 sV[2][64 * 64];
  const int tid = threadIdx.x, lane = tid & 63, wq = tid >> 6;
  const int h = lane >> 5, r31 = lane & 31;
  const int bh = blockIdx.x;
  const int qtb = (int)gridDim.y - 1 - (int)blockIdx.y;  // 0..31
  const int q0 = qtb * 128;
  const int ntile = 2 * qtb + 2;
  const hbf* Q  = qkv + (size_t)bh * 262144;
  const hbf* Kp = qkv + (size_t)(32 + bh) * 262144;
  const hbf* Vp = qkv + (size_t)(64 + bh) * 262144;  // [e=64][t=4096]
  const float NEG_INF = -__builtin_inff();

  const int koff = (wq * 16 + (lane >> 3)) * 64 + (((lane & 7) ^ (lane >> 3)) * 8);
  const int voff = (wq * 16 + (lane >> 3)) * 4096 + (((lane & 7) ^ (lane >> 3)) * 8);

  const int qrow = q0 + wq * 32 + r31;
  bf16x8 aq[4];
#pragma unroll
  for (int ks = 0; ks < 4; ++ks)
    aq[ks] = *reinterpret_cast<const bf16x8*>(Q + (size_t)qrow * 64 + ks * 16 + h * 8);

  f32x16 accO[2];
#pragma unroll
  for (int et = 0; et < 2; ++et)
#pragma unroll
    for (int i = 0; i < 16; ++i) accO[et][i] = 0.f;
  float mrow = NEG_INF, lrow = 0.f;  // lane owns q-row r31's stats

  // prologue: stage tile 0 into buf 0
  gload_lds16(Kp + koff,         &sK[0][wq * 1024]);
  gload_lds16(Kp + koff + 512,   &sK[0][wq * 1024 + 512]);
  gload_lds16(Vp + voff,         &sV[0][wq * 1024]);
  gload_lds16(Vp + voff + 32768, &sV[0][wq * 1024 + 512]);
  __syncthreads();

  const int qmaxw = q0 + wq * 32 + 31;
  int buf = 0;
  for (int jt = 0; jt < ntile; ++jt) {
    if (jt < ntile - 1) {  // prefetch next tile (pure DMA)
      const hbf* Kg = Kp + (size_t)(jt + 1) * 4096;
      gload_lds16(Kg + koff,       &sK[buf ^ 1][wq * 1024]);
      gload_lds16(Kg + koff + 512, &sK[buf ^ 1][wq * 1024 + 512]);
      const hbf* Vg = Vp + (jt + 1) * 64;
      gload_lds16(Vg + voff,         &sV[buf ^ 1][wq * 1024]);
      gload_lds16(Vg + voff + 32768, &sV[buf ^ 1][wq * 1024 + 512]);
    }

    if (64 * jt <= qmaxw) {  // wave has unmasked work in this tile
      const __bf16* sKb = sK[buf];
      const __bf16* sVb = sV[buf];

      // S^T = K Q^T : two 32kv x 32q tiles
      f32x16 accS[2];
      __builtin_amdgcn_s_setprio(1);
#pragma unroll
      for (int t = 0; t < 2; ++t) {
        f32x16 s;
#pragma unroll
        for (int i = 0; i < 16; ++i) s[i] = 0.f;
#pragma unroll
        for (int ks = 0; ks < 4; ++ks) {
          bf16x8 ak = *reinterpret_cast<const bf16x8*>(
              sKb + (t * 32 + r31) * 64 + (((2 * ks + h) ^ (r31 & 7)) * 8));
          s = __builtin_amdgcn_mfma_f32_32x32x16_bf16(ak, aq[ks], s, 0, 0, 0);
        }
        accS[t] = s;
      }
      __builtin_amdgcn_s_setprio(0);

      if (64 * jt + 63 > q0 + wq * 32) {  // diagonal region: mask kv > q
#pragma unroll
        for (int t = 0; t < 2; ++t)
#pragma unroll
          for (int i = 0; i < 16; ++i) {
            const int kvg = 64 * jt + 32 * t + (i & 3) + 8 * (i >> 2) + 4 * h;
            if (kvg > qrow) accS[t][i] = NEG_INF;
          }
      }

      // row max: max3 tree (v_max3_f32 fusion), then cross-half exchange
      float g0 = max3f(accS[0][0], accS[0][1], accS[0][2]);
      float g1 = max3f(accS[0][3], accS[0][4], accS[0][5]);
      float g2 = max3f(accS[0][6], accS[0][7], accS[0][8]);
      float g3 = max3f(accS[0][9], accS[0][10], accS[0][11]);
      float g4 = max3f(accS[0][12], accS[0][13], accS[0][14]);
      float g5 = max3f(accS[0][15], accS[1][0], accS[1][1]);
      float g6 = max3f(accS[1][2], accS[1][3], accS[1][4]);
      float g7 = max3f(accS[1][5], accS[1][6], accS[1][7]);
      float g8 = max3f(accS[1][8], accS[1][9], accS[1][10]);
      float g9 = max3f(accS[1][11], accS[1][12], accS[1][13]);
      float gA = fmaxf(accS[1][14], accS[1][15]);
      float h0 = max3f(g0, g1, g2);
      float h1 = max3f(g3, g4, g5);
      float h2 = max3f(g6, g7, g8);
      float h3 = fmaxf(g9, gA);
      float pmax = fmaxf(max3f(h0, h1, h2), h3);
      pmax = fmaxf(pmax, __shfl_xor(pmax, 32));

      if (!__all(pmax - mrow <= 8.f)) {  // defer-rescale (T13)
        const float mn = fmaxf(mrow, pmax);
        const float corr = __builtin_amdgcn_exp2f(mrow - mn);
        mrow = mn;
        lrow *= corr;
#pragma unroll
        for (int et = 0; et < 2; ++et)
#pragma unroll
          for (int i = 0; i < 16; ++i) accO[et][i] *= corr;
      }

      // p = exp2(S - m) in place; row-sum
#pragma unroll
      for (int t = 0; t < 2; ++t)
#pragma unroll
        for (int i = 0; i < 16; ++i)
          accS[t][i] = __builtin_amdgcn_exp2f(accS[t][i] - mrow);
      float s0 = (accS[0][0] + accS[0][1]) + (accS[0][2] + accS[0][3]);
      float s1 = (accS[0][4] + accS[0][5]) + (accS[0][6] + accS[0][7]);
      float s2 = (accS[0][8] + accS[0][9]) + (accS[0][10] + accS[0][11]);
      float s3 = (accS[0][12] + accS[0][13]) + (accS[0][14] + accS[0][15]);
      float s4 = (accS[1][0] + accS[1][1]) + (accS[1][2] + accS[1][3]);
      float s5 = (accS[1][4] + accS[1][5]) + (accS[1][6] + accS[1][7]);
      float s6 = (accS[1][8] + accS[1][9]) + (accS[1][10] + accS[1][11]);
      float s7 = (accS[1][12] + accS[1][13]) + (accS[1][14] + accS[1][15]);
      float rs = ((s0 + s1) + (s2 + s3)) + ((s4 + s5) + (s6 + s7));
      rs += __shfl_xor(rs, 32);
      lrow += rs;

      // pack to bf16 dwords: d0/d1[t][r4]
      uint32_t d0[2][4], d1[2][4];
#pragma unroll
      for (int t = 0; t < 2; ++t)
#pragma unroll
        for (int r4 = 0; r4 < 4; ++r4) {
          d0[t][r4] = cvtpk(accS[t][4 * r4 + 0], accS[t][4 * r4 + 1]);
          d1[t][r4] = cvtpk(accS[t][4 * r4 + 2], accS[t][4 * r4 + 3]);
        }

      // PV: u[0] = newX of swap(d[ra], d[rb]) ; u[2] = newY (R9-verified)
#pragma unroll
      for (int kb = 0; kb < 4; ++kb) {
        const int t = kb >> 1, ra = 2 * (kb & 1), rb = ra + 1;
        uint32_t x0 = d0[t][ra], y0 = d0[t][rb];
        uint32_t x1 = d1[t][ra], y1 = d1[t][rb];
        pl32swap(x0, y0);
        pl32swap(x1, y1);
        union { uint32_t u[4]; bf16x8 v; } bP;
        bP.u[0] = x0; bP.u[1] = x1; bP.u[2] = y0; bP.u[3] = y1;
        __builtin_amdgcn_s_setprio(1);
#pragma unroll
        for (int et = 0; et < 2; ++et) {
          bf16x8 av = *reinterpret_cast<const bf16x8*>(
              sVb + (et * 32 + r31) * 64 + (((2 * kb + h) ^ (r31 & 7)) * 8));
          accO[et] = __builtin_amdgcn_mfma_f32_32x32x16_bf16(av, bP.v, accO[et], 0, 0, 0);
        }
        __builtin_amdgcn_s_setprio(0);
      }
    }

    __syncthreads();  // drains K/V DMA; all waves done with buf
    buf ^= 1;
  }

  // epilogue: accO[et][i] = O^T[e = (i&3)+8*(i>>2)+4h+32et][q = r31]
  const float inv = 1.0f / lrow;
  hbf* arow = attn + ((size_t)(bh >> 4) * 4096 + qrow) * 1024 + (bh & 15) * 64;
#pragma unroll
  for (int et = 0; et < 2; ++et)
#pragma unroll
    for (int r4 = 0; r4 < 4; ++r4) {
      const int e0 = et * 32 + 8 * r4 + 4 * h;
      ushort4 o;
      o.x = b2u(accO[et][4 * r4 + 0] * inv);
      o.y = b2u(accO[et][4 * r4 + 1] * inv);
      o.z = b2u(accO[et][4 * r4 + 2] * inv);
      o.w = b2u(accO[et][4 * r4 + 3] * inv);
      *reinterpret_cast<ushort4*>(arow + e0) = o;
    }
}

// ---------------- output projection GEMM ----------------
// XCD-chunked swizzle (512 wgs, 64/XCD).

__global__ __launch_bounds__(256) void k_gemm_out(
    const hbf* __restrict__ A, const hbf* __restrict__ Bw,
    const float* __restrict__ bp, float* __restrict__ out) {
  __shared__ __align__(16) hbf sA[128 * 64];
  __shared__ __align__(16) hbf sB[128 * 64];
  const int tid = threadIdx.x;
  const int lane = tid & 63, wid = tid >> 6;
  int wg = blockIdx.y * 64 + blockIdx.x;       // 0..511
  wg = (wg & 7) * 64 + (wg >> 3);              // bijective XCD chunking
  const int m0 = (wg & 63) * 128, n0 = (wg >> 6) * 128;
  const int g = lane >> 4, cl = lane & 15;

  const f32x4 fz = {0.f, 0.f, 0.f, 0.f};
  f32x4 acc[4][4];
#pragma unroll
  for (int a = 0; a < 4; ++a)
#pragma unroll
    for (int b = 0; b < 4; ++b) acc[a][b] = fz;

  const int srow = wid * 32 + (lane >> 3);
  const int scol = (lane & 7) * 8;

  for (int kt = 0; kt < 16; ++kt) {
    const int k0 = kt * 64;
#pragma unroll
    for (int t = 0; t < 4; ++t) {
      const int r = srow + t * 8;
      gload_lds16(A + (size_t)(m0 + r) * 1024 + k0 + scol, sA + (wid * 32 + t * 8) * 64);
      gload_lds16(Bw + (size_t)(n0 + r) * 1024 + k0 + scol, sB + (wid * 32 + t * 8) * 64);
    }
    __syncthreads();
#pragma unroll
    for (int ks = 0; ks < 2; ++ks) {
      const int ko = ks * 32 + g * 8;
      bf16x8 af[4], bfr[4];
#pragma unroll
      for (int rt = 0; rt < 4; ++rt)
        af[rt] = *reinterpret_cast<const bf16x8*>(sA + ((wid & 1) * 64 + rt * 16 + cl) * 64 + ko);
#pragma unroll
      for (int ct = 0; ct < 4; ++ct)
        bfr[ct] = *reinterpret_cast<const bf16x8*>(sB + ((wid >> 1) * 64 + ct * 16 + cl) * 64 + ko);
#pragma unroll
      for (int rt = 0; rt < 4; ++rt)
#pragma unroll
        for (int ct = 0; ct < 4; ++ct)
          acc[rt][ct] = __builtin_amdgcn_mfma_f32_16x16x32_bf16(af[rt], bfr[ct], acc[rt][ct], 0, 0, 0);
    }
    __syncthreads();
  }

#pragma unroll
  for (int rt = 0; rt < 4; ++rt)
#pragma unroll
    for (int ct = 0; ct < 4; ++ct) {
      const int colg = n0 + (wid >> 1) * 64 + ct * 16 + cl;
      const float bi = bp[colg];
#pragma unroll
      for (int i = 0; i < 4; ++i) {
        const int rowg = m0 + (wid & 1) * 64 + rt * 16 + g * 4 + i;
        out[(size_t)rowg * 1024 + colg] = acc[rt][ct][i] + bi;
      }
    }
}

// ---------------- launcher ----------------

extern "C" void kernel_launch(void* const* d_in, const int* in_sizes, int n_in,
                              void* d_out, int out_size, void* d_ws, size_t ws_size,
                              hipStream_t stream) {
  const float* x  = (const float*)d_in[0];
  const float* Wq = (const float*)d_in[1];
  const float* Wk = (const float*)d_in[2];
  const float* Wv = (const float*)d_in[3];
  const float* bq = (const float*)d_in[4];
  const float* bk = (const float*)d_in[5];
  const float* bv = (const float*)d_in[6];
  const float* Wp = (const float*)d_in[7];
  const float* bp = (const float*)d_in[8];
  float* out = (float*)d_out;

  char* ws = (char*)d_ws;
  hbf*   xb    = (hbf*)ws;                                   // 16 MiB (reused as attn_out)
  hbf*   Wt    = (hbf*)(ws + 16777216);                      // 6 MiB
  hbf*   Wpt   = (hbf*)(ws + 16777216 + 6291456);            // 2 MiB
  float* biasc = (float*)(ws + 16777216 + 6291456 + 2097152);// 12 KiB (+pad)
  hbf*   qkv   = (hbf*)(ws + 16777216 + 6291456 + 2097152 + 16384); // 48 MiB
  hbf*   attn  = xb;

  k_cvt_all<<<24588, 256, 0, stream>>>(x, Wq, Wk, Wv, bq, bk, bv, Wp,
                                       xb, Wt, Wpt, biasc);

  dim3 g1(64, 24); k_gemm_qkv<<<g1, 256, 0, stream>>>(xb, Wt, biasc, qkv);
  dim3 g2(32, 32); k_flash   <<<g2, 256, 0, stream>>>(qkv, attn);
  dim3 g3(64, 8);  k_gemm_out<<<g3, 256, 0, stream>>>(attn, Wpt, bp, out);
}

// Round 12
// 219.031 us; speedup vs baseline: 1.1535x; 1.1159x over previous
//
#include <hip/hip_runtime.h>
#include <hip/hip_bf16.h>
#include <stdint.h>

// B=2, T=4096, D=1024, H=16, HS=64. Pipeline:
// fused cvt -> GEMM qkv (8-phase counted-vmcnt 128x256 tile; V TRANSPOSED
// [bh][e][t]) -> flash attn (R11: 32x32 swapped MFMA, in-reg softmax, cvt_pk+
// permlane32_swap, defer-rescale, dbuf swizzled K/V) -> GEMM out (m97 128^2).

typedef __bf16 bf16x8 __attribute__((ext_vector_type(8)));
typedef float f32x4 __attribute__((ext_vector_type(4)));
typedef float f32x16 __attribute__((ext_vector_type(16)));
typedef __attribute__((address_space(1))) void gvoid_t;
typedef __attribute__((address_space(3))) void lvoid_t;

using hbf = __hip_bfloat16;

#define QSCALE (0.125f * 1.44269504088896f)  // 1/sqrt(HS) * log2(e)

static __device__ __forceinline__ void gload_lds16(const void* g, void* l) {
  __builtin_amdgcn_global_load_lds((gvoid_t*)g, (lvoid_t*)l, 16, 0, 0);
}

static __device__ __forceinline__ uint16_t b2u(float x) {
  hbf h = __float2bfloat16(x);
  return *reinterpret_cast<uint16_t*>(&h);
}

static __device__ __forceinline__ uint32_t cvtpk(float lo, float hi) {
  uint32_t r;
  asm("v_cvt_pk_bf16_f32 %0, %1, %2" : "=v"(r) : "v"(lo), "v"(hi));
  return r;
}

// v_permlane32_swap_b32: newX = {X.lo31 | Y.lo31->hi}, newY = {X.hi31->lo | Y.hi31}
static __device__ __forceinline__ void pl32swap(uint32_t& x, uint32_t& y) {
  asm volatile("v_permlane32_swap_b32 %0, %1" : "+v"(x), "+v"(y));
}

static __device__ __forceinline__ float max3f(float a, float b, float c) {
  return fmaxf(fmaxf(a, b), c);  // fuses to v_max3_f32
}

// ---------------- fused converters ----------------

__global__ void k_cvt_all(const float* __restrict__ x,
                          const float* __restrict__ Wq, const float* __restrict__ Wk,
                          const float* __restrict__ Wv,
                          const float* __restrict__ bq, const float* __restrict__ bk,
                          const float* __restrict__ bv,
                          const float* __restrict__ Wp,
                          hbf* __restrict__ xb, hbf* __restrict__ Wt,
                          hbf* __restrict__ Wpt, float* __restrict__ biasc) {
  const int b = blockIdx.x, tid = threadIdx.x;
  if (b < 8192) {
    int i = (b * 256 + tid) * 4;
    float4 v = *reinterpret_cast<const float4*>(x + i);
    hbf h[4] = {__float2bfloat16(v.x), __float2bfloat16(v.y),
                __float2bfloat16(v.z), __float2bfloat16(v.w)};
    *reinterpret_cast<ushort4*>(xb + i) = *reinterpret_cast<ushort4*>(h);
  } else if (b < 20480) {
    int idx = (b - 8192) * 256 + tid;   // 3072*1024
    int d = idx & 1023, r = idx >> 10;
    int m = r >> 10, rem = r & 1023;
    int h = rem >> 6, e = rem & 63;
    const float* W = (m == 0) ? Wq : (m == 1) ? Wk : Wv;
    float v = W[(h << 10 | d) * 64 + e];
    if (m == 0) v *= QSCALE;
    Wt[idx] = __float2bfloat16(v);
  } else if (b < 24576) {
    int idx = (b - 20480) * 256 + tid;  // 1024*1024
    int o = idx >> 10, d = idx & 1023;
    Wpt[idx] = __float2bfloat16(Wp[(d << 10) + o]);
  } else {
    int r = (b - 24576) * 256 + tid;    // 0..3071
    int m = r >> 10, rem = r & 1023;
    const float* bsrc = (m == 0) ? bq : (m == 1) ? bk : bv;
    float v = bsrc[rem];
    if (m == 0) v *= QSCALE;
    biasc[r] = v;
  }
}

// ---------------- QKV projection GEMM (8-phase) ----------------
// Tile 128x256, 8 waves (2m x 4n), BK=64, LDS 2-buf 96KB, chunk-XOR swizzle.
// Per K-tile: ph0 {16 ds_read -> bar -> lgkm0 -> 8 MFMA -> bar};
// ph1..3 {2 gload_lds(kt+2) ; 8 MFMA ; bar}; vmcnt(6) at tile boundary only.
// Q,K -> qkv[mi][bh][t][e] ; V -> transposed [bh][e][t] (packed 8B stores).

__global__ __launch_bounds__(512) void k_gemm_qkv(
    const hbf* __restrict__ A, const hbf* __restrict__ Bw,
    const float* __restrict__ biasc, hbf* __restrict__ qkv) {
  __shared__ __align__(16) hbf sA[2][128 * 64];
  __shared__ __align__(16) hbf sB[2][256 * 64];
  const int tid = threadIdx.x;
  const int lane = tid & 63, w = tid >> 6;
  const int wm = w >> 2, wn = w & 3;
  const int g = lane >> 4, cl = lane & 15;
  const int m0 = blockIdx.x * 128, n0 = blockIdx.y * 256;

  // staging: thread covers row (s*64 + tid>>3), chunk tid&7 (16B units)
  const int sr = tid >> 3, sc = tid & 7;

  const f32x4 fz = {0.f, 0.f, 0.f, 0.f};
  f32x4 acc[4][4];
#pragma unroll
  for (int a = 0; a < 4; ++a)
#pragma unroll
    for (int b = 0; b < 4; ++b) acc[a][b] = fz;

  // prologue: stage tiles 0 and 1 (6 loads each: A s0,s1 ; B s0..s3)
#pragma unroll
  for (int kt = 0; kt < 2; ++kt) {
#pragma unroll
    for (int s = 0; s < 2; ++s) {
      const int row = s * 64 + sr;
      gload_lds16(A + (size_t)(m0 + row) * 1024 + kt * 64 + ((sc ^ (row & 7)) * 8),
                  &sA[kt][s * 4096 + tid * 8]);
    }
#pragma unroll
    for (int s = 0; s < 4; ++s) {
      const int row = s * 64 + sr;
      gload_lds16(Bw + (size_t)(n0 + row) * 1024 + kt * 64 + ((sc ^ (row & 7)) * 8),
                  &sB[kt][s * 4096 + tid * 8]);
    }
  }
  asm volatile("s_waitcnt vmcnt(6)" ::: "memory");  // tile 0 complete
  __builtin_amdgcn_s_barrier();

  for (int kt = 0; kt < 16; ++kt) {
    const int bi = kt & 1;
    const bool st = (kt + 2) < 16;

    // phase 0: read ALL fragments of tile kt (swizzled, 2-way free)
    bf16x8 af[4][2], bf[4][2];
#pragma unroll
    for (int rt = 0; rt < 4; ++rt)
#pragma unroll
      for (int ks = 0; ks < 2; ++ks)
        af[rt][ks] = *reinterpret_cast<const bf16x8*>(
            &sA[bi][(wm * 64 + rt * 16 + cl) * 64 + (((ks * 4 + g) ^ (cl & 7)) * 8)]);
#pragma unroll
    for (int ct = 0; ct < 4; ++ct)
#pragma unroll
      for (int ks = 0; ks < 2; ++ks)
        bf[ct][ks] = *reinterpret_cast<const bf16x8*>(
            &sB[bi][(wn * 64 + ct * 16 + cl) * 64 + (((ks * 4 + g) ^ (cl & 7)) * 8)]);
    __builtin_amdgcn_s_barrier();
    asm volatile("s_waitcnt lgkmcnt(0)" ::: "memory");
    __builtin_amdgcn_sched_barrier(0);  // rule #18: keep MFMA below the wait
    __builtin_amdgcn_s_setprio(1);
#pragma unroll
    for (int rt = 0; rt < 4; ++rt)
#pragma unroll
      for (int ks = 0; ks < 2; ++ks)
        acc[rt][0] = __builtin_amdgcn_mfma_f32_16x16x32_bf16(af[rt][ks], bf[0][ks], acc[rt][0], 0, 0, 0);
    __builtin_amdgcn_s_setprio(0);
    __builtin_amdgcn_s_barrier();  // all waves done reading buf[bi] -> free

    // phases 1..3: stage tile kt+2 into buf[bi] (2 loads/phase) || MFMA quad q
#pragma unroll
    for (int q = 1; q < 4; ++q) {
      if (st) {
        if (q == 1) {
#pragma unroll
          for (int s = 0; s < 2; ++s) {
            const int row = s * 64 + sr;
            gload_lds16(A + (size_t)(m0 + row) * 1024 + (kt + 2) * 64 + ((sc ^ (row & 7)) * 8),
                        &sA[bi][s * 4096 + tid * 8]);
          }
        } else {
#pragma unroll
          for (int s2 = 0; s2 < 2; ++s2) {
            const int s = (q - 2) * 2 + s2;
            const int row = s * 64 + sr;
            gload_lds16(Bw + (size_t)(n0 + row) * 1024 + (kt + 2) * 64 + ((sc ^ (row & 7)) * 8),
                        &sB[bi][s * 4096 + tid * 8]);
          }
        }
      }
      __builtin_amdgcn_s_setprio(1);
#pragma unroll
      for (int rt = 0; rt < 4; ++rt)
#pragma unroll
        for (int ks = 0; ks < 2; ++ks)
          acc[rt][q] = __builtin_amdgcn_mfma_f32_16x16x32_bf16(af[rt][ks], bf[q][ks], acc[rt][q], 0, 0, 0);
      __builtin_amdgcn_s_setprio(0);
      if (q == 3) {  // tile boundary: retire tile kt+1's loads, keep kt+2's in flight
        if (st) asm volatile("s_waitcnt vmcnt(6)" ::: "memory");
        else    asm volatile("s_waitcnt vmcnt(0)" ::: "memory");
      }
      __builtin_amdgcn_s_barrier();
    }
  }

  // epilogue (verified mapping): row = m0+wm*64+rt*16+g*4+i, col = n0+wn*64+ct*16+cl
#pragma unroll
  for (int rt = 0; rt < 4; ++rt)
#pragma unroll
    for (int ct = 0; ct < 4; ++ct) {
      const int colg = n0 + wn * 64 + ct * 16 + cl;
      const int mi = colg >> 10, rem = colg & 1023;
      const int h = rem >> 6, e = rem & 63;
      const float bi_ = biasc[colg];
      if (mi == 2) {
        const int t0 = m0 + wm * 64 + rt * 16 + g * 4;
        const int b = t0 >> 12, t = t0 & 4095;
        ushort4 o;
        o.x = b2u(acc[rt][ct][0] + bi_);
        o.y = b2u(acc[rt][ct][1] + bi_);
        o.z = b2u(acc[rt][ct][2] + bi_);
        o.w = b2u(acc[rt][ct][3] + bi_);
        *reinterpret_cast<ushort4*>(
            qkv + (size_t)64 * 262144 + (size_t)(b * 16 + h) * 262144 + (size_t)e * 4096 + t) = o;
      } else {
#pragma unroll
        for (int i = 0; i < 4; ++i) {
          const int rowg = m0 + wm * 64 + rt * 16 + g * 4 + i;
          const int b = rowg >> 12, t = rowg & 4095;
          qkv[(((size_t)mi * 32 + b * 16 + h) * 4096 + t) * 64 + e] =
              __float2bfloat16(acc[rt][ct][i] + bi_);
        }
      }
    }
}

// ---------------- flash attention (R11, verified) ----------------

__global__ __launch_bounds__(256) void k_flash(
    const hbf* __restrict__ qkv, hbf* __restrict__ attn) {
  __shared__ __align__(16) __bf16 sK[2][64 * 64];
  __shared__ __align__(16) __bf16 sV[2][64 * 64];
  const int tid = threadIdx.x, lane = tid & 63, wq = tid >> 6;
  const int h = lane >> 5, r31 = lane & 31;
  const int bh = blockIdx.x;
  const int qtb = (int)gridDim.y - 1 - (int)blockIdx.y;  // 0..31
  const int q0 = qtb * 128;
  const int ntile = 2 * qtb + 2;
  const hbf* Q  = qkv + (size_t)bh * 262144;
  const hbf* Kp = qkv + (size_t)(32 + bh) * 262144;
  const hbf* Vp = qkv + (size_t)(64 + bh) * 262144;  // [e=64][t=4096]
  const float NEG_INF = -__builtin_inff();

  const int koff = (wq * 16 + (lane >> 3)) * 64 + (((lane & 7) ^ (lane >> 3)) * 8);
  const int voff = (wq * 16 + (lane >> 3)) * 4096 + (((lane & 7) ^ (lane >> 3)) * 8);

  const int qrow = q0 + wq * 32 + r31;
  bf16x8 aq[4];
#pragma unroll
  for (int ks = 0; ks < 4; ++ks)
    aq[ks] = *reinterpret_cast<const bf16x8*>(Q + (size_t)qrow * 64 + ks * 16 + h * 8);

  f32x16 accO[2];
#pragma unroll
  for (int et = 0; et < 2; ++et)
#pragma unroll
    for (int i = 0; i < 16; ++i) accO[et][i] = 0.f;
  float mrow = NEG_INF, lrow = 0.f;

  gload_lds16(Kp + koff,         &sK[0][wq * 1024]);
  gload_lds16(Kp + koff + 512,   &sK[0][wq * 1024 + 512]);
  gload_lds16(Vp + voff,         &sV[0][wq * 1024]);
  gload_lds16(Vp + voff + 32768, &sV[0][wq * 1024 + 512]);
  __syncthreads();

  const int qmaxw = q0 + wq * 32 + 31;
  int buf = 0;
  for (int jt = 0; jt < ntile; ++jt) {
    if (jt < ntile - 1) {
      const hbf* Kg = Kp + (size_t)(jt + 1) * 4096;
      gload_lds16(Kg + koff,       &sK[buf ^ 1][wq * 1024]);
      gload_lds16(Kg + koff + 512, &sK[buf ^ 1][wq * 1024 + 512]);
      const hbf* Vg = Vp + (jt + 1) * 64;
      gload_lds16(Vg + voff,         &sV[buf ^ 1][wq * 1024]);
      gload_lds16(Vg + voff + 32768, &sV[buf ^ 1][wq * 1024 + 512]);
    }

    if (64 * jt <= qmaxw) {
      const __bf16* sKb = sK[buf];
      const __bf16* sVb = sV[buf];

      f32x16 accS[2];
      __builtin_amdgcn_s_setprio(1);
#pragma unroll
      for (int t = 0; t < 2; ++t) {
        f32x16 s;
#pragma unroll
        for (int i = 0; i < 16; ++i) s[i] = 0.f;
#pragma unroll
        for (int ks = 0; ks < 4; ++ks) {
          bf16x8 ak = *reinterpret_cast<const bf16x8*>(
              sKb + (t * 32 + r31) * 64 + (((2 * ks + h) ^ (r31 & 7)) * 8));
          s = __builtin_amdgcn_mfma_f32_32x32x16_bf16(ak, aq[ks], s, 0, 0, 0);
        }
        accS[t] = s;
      }
      __builtin_amdgcn_s_setprio(0);

      if (64 * jt + 63 > q0 + wq * 32) {
#pragma unroll
        for (int t = 0; t < 2; ++t)
#pragma unroll
          for (int i = 0; i < 16; ++i) {
            const int kvg = 64 * jt + 32 * t + (i & 3) + 8 * (i >> 2) + 4 * h;
            if (kvg > qrow) accS[t][i] = NEG_INF;
          }
      }

      float g0 = max3f(accS[0][0], accS[0][1], accS[0][2]);
      float g1 = max3f(accS[0][3], accS[0][4], accS[0][5]);
      float g2 = max3f(accS[0][6], accS[0][7], accS[0][8]);
      float g3 = max3f(accS[0][9], accS[0][10], accS[0][11]);
      float g4 = max3f(accS[0][12], accS[0][13], accS[0][14]);
      float g5 = max3f(accS[0][15], accS[1][0], accS[1][1]);
      float g6 = max3f(accS[1][2], accS[1][3], accS[1][4]);
      float g7 = max3f(accS[1][5], accS[1][6], accS[1][7]);
      float g8 = max3f(accS[1][8], accS[1][9], accS[1][10]);
      float g9 = max3f(accS[1][11], accS[1][12], accS[1][13]);
      float gA = fmaxf(accS[1][14], accS[1][15]);
      float h0 = max3f(g0, g1, g2);
      float h1 = max3f(g3, g4, g5);
      float h2 = max3f(g6, g7, g8);
      float h3 = fmaxf(g9, gA);
      float pmax = fmaxf(max3f(h0, h1, h2), h3);
      pmax = fmaxf(pmax, __shfl_xor(pmax, 32));

      if (!__all(pmax - mrow <= 8.f)) {
        const float mn = fmaxf(mrow, pmax);
        const float corr = __builtin_amdgcn_exp2f(mrow - mn);
        mrow = mn;
        lrow *= corr;
#pragma unroll
        for (int et = 0; et < 2; ++et)
#pragma unroll
          for (int i = 0; i < 16; ++i) accO[et][i] *= corr;
      }

#pragma unroll
      for (int t = 0; t < 2; ++t)
#pragma unroll
        for (int i = 0; i < 16; ++i)
          accS[t][i] = __builtin_amdgcn_exp2f(accS[t][i] - mrow);
      float s0 = (accS[0][0] + accS[0][1]) + (accS[0][2] + accS[0][3]);
      float s1 = (accS[0][4] + accS[0][5]) + (accS[0][6] + accS[0][7]);
      float s2 = (accS[0][8] + accS[0][9]) + (accS[0][10] + accS[0][11]);
      float s3 = (accS[0][12] + accS[0][13]) + (accS[0][14] + accS[0][15]);
      float s4 = (accS[1][0] + accS[1][1]) + (accS[1][2] + accS[1][3]);
      float s5 = (accS[1][4] + accS[1][5]) + (accS[1][6] + accS[1][7]);
      float s6 = (accS[1][8] + accS[1][9]) + (accS[1][10] + accS[1][11]);
      float s7 = (accS[1][12] + accS[1][13]) + (accS[1][14] + accS[1][15]);
      float rs = ((s0 + s1) + (s2 + s3)) + ((s4 + s5) + (s6 + s7));
      rs += __shfl_xor(rs, 32);
      lrow += rs;

      uint32_t d0[2][4], d1[2][4];
#pragma unroll
      for (int t = 0; t < 2; ++t)
#pragma unroll
        for (int r4 = 0; r4 < 4; ++r4) {
          d0[t][r4] = cvtpk(accS[t][4 * r4 + 0], accS[t][4 * r4 + 1]);
          d1[t][r4] = cvtpk(accS[t][4 * r4 + 2], accS[t][4 * r4 + 3]);
        }

#pragma unroll
      for (int kb = 0; kb < 4; ++kb) {
        const int t = kb >> 1, ra = 2 * (kb & 1), rb = ra + 1;
        uint32_t x0 = d0[t][ra], y0 = d0[t][rb];
        uint32_t x1 = d1[t][ra], y1 = d1[t][rb];
        pl32swap(x0, y0);
        pl32swap(x1, y1);
        union { uint32_t u[4]; bf16x8 v; } bP;
        bP.u[0] = x0; bP.u[1] = x1; bP.u[2] = y0; bP.u[3] = y1;
        __builtin_amdgcn_s_setprio(1);
#pragma unroll
        for (int et = 0; et < 2; ++et) {
          bf16x8 av = *reinterpret_cast<const bf16x8*>(
              sVb + (et * 32 + r31) * 64 + (((2 * kb + h) ^ (r31 & 7)) * 8));
          accO[et] = __builtin_amdgcn_mfma_f32_32x32x16_bf16(av, bP.v, accO[et], 0, 0, 0);
        }
        __builtin_amdgcn_s_setprio(0);
      }
    }

    __syncthreads();
    buf ^= 1;
  }

  const float inv = 1.0f / lrow;
  hbf* arow = attn + ((size_t)(bh >> 4) * 4096 + qrow) * 1024 + (bh & 15) * 64;
#pragma unroll
  for (int et = 0; et < 2; ++et)
#pragma unroll
    for (int r4 = 0; r4 < 4; ++r4) {
      const int e0 = et * 32 + 8 * r4 + 4 * h;
      ushort4 o;
      o.x = b2u(accO[et][4 * r4 + 0] * inv);
      o.y = b2u(accO[et][4 * r4 + 1] * inv);
      o.z = b2u(accO[et][4 * r4 + 2] * inv);
      o.w = b2u(accO[et][4 * r4 + 3] * inv);
      *reinterpret_cast<ushort4*>(arow + e0) = o;
    }
}

// ---------------- output projection GEMM (m97 128^2, no swizzle) ----------------

__global__ __launch_bounds__(256) void k_gemm_out(
    const hbf* __restrict__ A, const hbf* __restrict__ Bw,
    const float* __restrict__ bp, float* __restrict__ out) {
  __shared__ __align__(16) hbf sA[128 * 64];
  __shared__ __align__(16) hbf sB[128 * 64];
  const int tid = threadIdx.x;
  const int lane = tid & 63, wid = tid >> 6;
  const int m0 = blockIdx.x * 128, n0 = blockIdx.y * 128;
  const int g = lane >> 4, cl = lane & 15;

  const f32x4 fz = {0.f, 0.f, 0.f, 0.f};
  f32x4 acc[4][4];
#pragma unroll
  for (int a = 0; a < 4; ++a)
#pragma unroll
    for (int b = 0; b < 4; ++b) acc[a][b] = fz;

  const int srow = wid * 32 + (lane >> 3);
  const int scol = (lane & 7) * 8;

  for (int kt = 0; kt < 16; ++kt) {
    const int k0 = kt * 64;
#pragma unroll
    for (int t = 0; t < 4; ++t) {
      const int r = srow + t * 8;
      gload_lds16(A + (size_t)(m0 + r) * 1024 + k0 + scol, sA + (wid * 32 + t * 8) * 64);
      gload_lds16(Bw + (size_t)(n0 + r) * 1024 + k0 + scol, sB + (wid * 32 + t * 8) * 64);
    }
    __syncthreads();
#pragma unroll
    for (int ks = 0; ks < 2; ++ks) {
      const int ko = ks * 32 + g * 8;
      bf16x8 af[4], bfr[4];
#pragma unroll
      for (int rt = 0; rt < 4; ++rt)
        af[rt] = *reinterpret_cast<const bf16x8*>(sA + ((wid & 1) * 64 + rt * 16 + cl) * 64 + ko);
#pragma unroll
      for (int ct = 0; ct < 4; ++ct)
        bfr[ct] = *reinterpret_cast<const bf16x8*>(sB + ((wid >> 1) * 64 + ct * 16 + cl) * 64 + ko);
#pragma unroll
      for (int rt = 0; rt < 4; ++rt)
#pragma unroll
        for (int ct = 0; ct < 4; ++ct)
          acc[rt][ct] = __builtin_amdgcn_mfma_f32_16x16x32_bf16(af[rt], bfr[ct], acc[rt][ct], 0, 0, 0);
    }
    __syncthreads();
  }

#pragma unroll
  for (int rt = 0; rt < 4; ++rt)
#pragma unroll
    for (int ct = 0; ct < 4; ++ct) {
      const int colg = n0 + (wid >> 1) * 64 + ct * 16 + cl;
      const float bi = bp[colg];
#pragma unroll
      for (int i = 0; i < 4; ++i) {
        const int rowg = m0 + (wid & 1) * 64 + rt * 16 + g * 4 + i;
        out[(size_t)rowg * 1024 + colg] = acc[rt][ct][i] + bi;
      }
    }
}

// ---------------- launcher ----------------

extern "C" void kernel_launch(void* const* d_in, const int* in_sizes, int n_in,
                              void* d_out, int out_size, void* d_ws, size_t ws_size,
                              hipStream_t stream) {
  const float* x  = (const float*)d_in[0];
  const float* Wq = (const float*)d_in[1];
  const float* Wk = (const float*)d_in[2];
  const float* Wv = (const float*)d_in[3];
  const float* bq = (const float*)d_in[4];
  const float* bk = (const float*)d_in[5];
  const float* bv = (const float*)d_in[6];
  const float* Wp = (const float*)d_in[7];
  const float* bp = (const float*)d_in[8];
  float* out = (float*)d_out;

  char* ws = (char*)d_ws;
  hbf*   xb    = (hbf*)ws;                                   // 16 MiB (reused as attn_out)
  hbf*   Wt    = (hbf*)(ws + 16777216);                      // 6 MiB
  hbf*   Wpt   = (hbf*)(ws + 16777216 + 6291456);            // 2 MiB
  float* biasc = (float*)(ws + 16777216 + 6291456 + 2097152);// 12 KiB (+pad)
  hbf*   qkv   = (hbf*)(ws + 16777216 + 6291456 + 2097152 + 16384); // 48 MiB
  hbf*   attn  = xb;

  k_cvt_all<<<24588, 256, 0, stream>>>(x, Wq, Wk, Wv, bq, bk, bv, Wp,
                                       xb, Wt, Wpt, biasc);

  dim3 g1(64, 12); k_gemm_qkv<<<g1, 512, 0, stream>>>(xb, Wt, biasc, qkv);
  dim3 g2(32, 32); k_flash   <<<g2, 256, 0, stream>>>(qkv, attn);
  dim3 g3(64, 8);  k_gemm_out<<<g3, 256, 0, stream>>>(attn, Wpt, bp, out);
}

// Round 13
// 212.371 us; speedup vs baseline: 1.1897x; 1.0314x over previous
//
#include <hip/hip_runtime.h>
#include <hip/hip_bf16.h>
#include <stdint.h>

// B=2, T=4096, D=1024, H=16, HS=64. Pipeline:
// fused cvt -> GEMM qkv (8-phase counted-vmcnt 128x256; V TRANSPOSED [bh][e][t])
// -> flash attn (32x32 swapped MFMA, in-reg softmax, cvt_pk+permlane32_swap,
// defer-rescale, dbuf swizzled K/V) -> GEMM out (8-phase 128x256, fp32 out).

typedef __bf16 bf16x8 __attribute__((ext_vector_type(8)));
typedef float f32x4 __attribute__((ext_vector_type(4)));
typedef float f32x16 __attribute__((ext_vector_type(16)));
typedef __attribute__((address_space(1))) void gvoid_t;
typedef __attribute__((address_space(3))) void lvoid_t;

using hbf = __hip_bfloat16;

#define QSCALE (0.125f * 1.44269504088896f)  // 1/sqrt(HS) * log2(e)

static __device__ __forceinline__ void gload_lds16(const void* g, void* l) {
  __builtin_amdgcn_global_load_lds((gvoid_t*)g, (lvoid_t*)l, 16, 0, 0);
}

static __device__ __forceinline__ uint16_t b2u(float x) {
  hbf h = __float2bfloat16(x);
  return *reinterpret_cast<uint16_t*>(&h);
}

static __device__ __forceinline__ uint32_t cvtpk(float lo, float hi) {
  uint32_t r;
  asm("v_cvt_pk_bf16_f32 %0, %1, %2" : "=v"(r) : "v"(lo), "v"(hi));
  return r;
}

// v_permlane32_swap_b32: newX = {X.lo31 | Y.lo31->hi}, newY = {X.hi31->lo | Y.hi31}
static __device__ __forceinline__ void pl32swap(uint32_t& x, uint32_t& y) {
  asm volatile("v_permlane32_swap_b32 %0, %1" : "+v"(x), "+v"(y));
}

static __device__ __forceinline__ float max3f(float a, float b, float c) {
  return fmaxf(fmaxf(a, b), c);  // fuses to v_max3_f32
}

// ---------------- fused converters ----------------

__global__ void k_cvt_all(const float* __restrict__ x,
                          const float* __restrict__ Wq, const float* __restrict__ Wk,
                          const float* __restrict__ Wv,
                          const float* __restrict__ bq, const float* __restrict__ bk,
                          const float* __restrict__ bv,
                          const float* __restrict__ Wp,
                          hbf* __restrict__ xb, hbf* __restrict__ Wt,
                          hbf* __restrict__ Wpt, float* __restrict__ biasc) {
  const int b = blockIdx.x, tid = threadIdx.x;
  if (b < 8192) {
    int i = (b * 256 + tid) * 4;
    float4 v = *reinterpret_cast<const float4*>(x + i);
    hbf h[4] = {__float2bfloat16(v.x), __float2bfloat16(v.y),
                __float2bfloat16(v.z), __float2bfloat16(v.w)};
    *reinterpret_cast<ushort4*>(xb + i) = *reinterpret_cast<ushort4*>(h);
  } else if (b < 20480) {
    int idx = (b - 8192) * 256 + tid;   // 3072*1024
    int d = idx & 1023, r = idx >> 10;
    int m = r >> 10, rem = r & 1023;
    int h = rem >> 6, e = rem & 63;
    const float* W = (m == 0) ? Wq : (m == 1) ? Wk : Wv;
    float v = W[(h << 10 | d) * 64 + e];
    if (m == 0) v *= QSCALE;
    Wt[idx] = __float2bfloat16(v);
  } else if (b < 24576) {
    int idx = (b - 20480) * 256 + tid;  // 1024*1024
    int o = idx >> 10, d = idx & 1023;
    Wpt[idx] = __float2bfloat16(Wp[(d << 10) + o]);
  } else {
    int r = (b - 24576) * 256 + tid;    // 0..3071
    int m = r >> 10, rem = r & 1023;
    const float* bsrc = (m == 0) ? bq : (m == 1) ? bk : bv;
    float v = bsrc[rem];
    if (m == 0) v *= QSCALE;
    biasc[r] = v;
  }
}

// ---------------- QKV projection GEMM (8-phase, R12-verified) ----------------

__global__ __launch_bounds__(512) void k_gemm_qkv(
    const hbf* __restrict__ A, const hbf* __restrict__ Bw,
    const float* __restrict__ biasc, hbf* __restrict__ qkv) {
  __shared__ __align__(16) hbf sA[2][128 * 64];
  __shared__ __align__(16) hbf sB[2][256 * 64];
  const int tid = threadIdx.x;
  const int lane = tid & 63, w = tid >> 6;
  const int wm = w >> 2, wn = w & 3;
  const int g = lane >> 4, cl = lane & 15;
  const int m0 = blockIdx.x * 128, n0 = blockIdx.y * 256;
  const int sr = tid >> 3, sc = tid & 7;

  const f32x4 fz = {0.f, 0.f, 0.f, 0.f};
  f32x4 acc[4][4];
#pragma unroll
  for (int a = 0; a < 4; ++a)
#pragma unroll
    for (int b = 0; b < 4; ++b) acc[a][b] = fz;

#pragma unroll
  for (int kt = 0; kt < 2; ++kt) {
#pragma unroll
    for (int s = 0; s < 2; ++s) {
      const int row = s * 64 + sr;
      gload_lds16(A + (size_t)(m0 + row) * 1024 + kt * 64 + ((sc ^ (row & 7)) * 8),
                  &sA[kt][s * 4096 + tid * 8]);
    }
#pragma unroll
    for (int s = 0; s < 4; ++s) {
      const int row = s * 64 + sr;
      gload_lds16(Bw + (size_t)(n0 + row) * 1024 + kt * 64 + ((sc ^ (row & 7)) * 8),
                  &sB[kt][s * 4096 + tid * 8]);
    }
  }
  asm volatile("s_waitcnt vmcnt(6)" ::: "memory");
  __builtin_amdgcn_s_barrier();

  for (int kt = 0; kt < 16; ++kt) {
    const int bi = kt & 1;
    const bool st = (kt + 2) < 16;

    bf16x8 af[4][2], bf[4][2];
#pragma unroll
    for (int rt = 0; rt < 4; ++rt)
#pragma unroll
      for (int ks = 0; ks < 2; ++ks)
        af[rt][ks] = *reinterpret_cast<const bf16x8*>(
            &sA[bi][(wm * 64 + rt * 16 + cl) * 64 + (((ks * 4 + g) ^ (cl & 7)) * 8)]);
#pragma unroll
    for (int ct = 0; ct < 4; ++ct)
#pragma unroll
      for (int ks = 0; ks < 2; ++ks)
        bf[ct][ks] = *reinterpret_cast<const bf16x8*>(
            &sB[bi][(wn * 64 + ct * 16 + cl) * 64 + (((ks * 4 + g) ^ (cl & 7)) * 8)]);
    __builtin_amdgcn_s_barrier();
    asm volatile("s_waitcnt lgkmcnt(0)" ::: "memory");
    __builtin_amdgcn_sched_barrier(0);
    __builtin_amdgcn_s_setprio(1);
#pragma unroll
    for (int rt = 0; rt < 4; ++rt)
#pragma unroll
      for (int ks = 0; ks < 2; ++ks)
        acc[rt][0] = __builtin_amdgcn_mfma_f32_16x16x32_bf16(af[rt][ks], bf[0][ks], acc[rt][0], 0, 0, 0);
    __builtin_amdgcn_s_setprio(0);
    __builtin_amdgcn_s_barrier();

#pragma unroll
    for (int q = 1; q < 4; ++q) {
      if (st) {
        if (q == 1) {
#pragma unroll
          for (int s = 0; s < 2; ++s) {
            const int row = s * 64 + sr;
            gload_lds16(A + (size_t)(m0 + row) * 1024 + (kt + 2) * 64 + ((sc ^ (row & 7)) * 8),
                        &sA[bi][s * 4096 + tid * 8]);
          }
        } else {
#pragma unroll
          for (int s2 = 0; s2 < 2; ++s2) {
            const int s = (q - 2) * 2 + s2;
            const int row = s * 64 + sr;
            gload_lds16(Bw + (size_t)(n0 + row) * 1024 + (kt + 2) * 64 + ((sc ^ (row & 7)) * 8),
                        &sB[bi][s * 4096 + tid * 8]);
          }
        }
      }
      __builtin_amdgcn_s_setprio(1);
#pragma unroll
      for (int rt = 0; rt < 4; ++rt)
#pragma unroll
        for (int ks = 0; ks < 2; ++ks)
          acc[rt][q] = __builtin_amdgcn_mfma_f32_16x16x32_bf16(af[rt][ks], bf[q][ks], acc[rt][q], 0, 0, 0);
      __builtin_amdgcn_s_setprio(0);
      if (q == 3) {
        if (st) asm volatile("s_waitcnt vmcnt(6)" ::: "memory");
        else    asm volatile("s_waitcnt vmcnt(0)" ::: "memory");
      }
      __builtin_amdgcn_s_barrier();
    }
  }

#pragma unroll
  for (int rt = 0; rt < 4; ++rt)
#pragma unroll
    for (int ct = 0; ct < 4; ++ct) {
      const int colg = n0 + wn * 64 + ct * 16 + cl;
      const int mi = colg >> 10, rem = colg & 1023;
      const int h = rem >> 6, e = rem & 63;
      const float bi_ = biasc[colg];
      if (mi == 2) {
        const int t0 = m0 + wm * 64 + rt * 16 + g * 4;
        const int b = t0 >> 12, t = t0 & 4095;
        ushort4 o;
        o.x = b2u(acc[rt][ct][0] + bi_);
        o.y = b2u(acc[rt][ct][1] + bi_);
        o.z = b2u(acc[rt][ct][2] + bi_);
        o.w = b2u(acc[rt][ct][3] + bi_);
        *reinterpret_cast<ushort4*>(
            qkv + (size_t)64 * 262144 + (size_t)(b * 16 + h) * 262144 + (size_t)e * 4096 + t) = o;
      } else {
#pragma unroll
        for (int i = 0; i < 4; ++i) {
          const int rowg = m0 + wm * 64 + rt * 16 + g * 4 + i;
          const int b = rowg >> 12, t = rowg & 4095;
          qkv[(((size_t)mi * 32 + b * 16 + h) * 4096 + t) * 64 + e] =
              __float2bfloat16(acc[rt][ct][i] + bi_);
        }
      }
    }
}

// ---------------- flash attention (R11/R12, verified) ----------------

__global__ __launch_bounds__(256) void k_flash(
    const hbf* __restrict__ qkv, hbf* __restrict__ attn) {
  __shared__ __align__(16) __bf16 sK[2][64 * 64];
  __shared__ __align__(16) __bf16 sV[2][64 * 64];
  const int tid = threadIdx.x, lane = tid & 63, wq = tid >> 6;
  const int h = lane >> 5, r31 = lane & 31;
  const int bh = blockIdx.x;
  const int qtb = (int)gridDim.y - 1 - (int)blockIdx.y;  // 0..31
  const int q0 = qtb * 128;
  const int ntile = 2 * qtb + 2;
  const hbf* Q  = qkv + (size_t)bh * 262144;
  const hbf* Kp = qkv + (size_t)(32 + bh) * 262144;
  const hbf* Vp = qkv + (size_t)(64 + bh) * 262144;  // [e=64][t=4096]
  const float NEG_INF = -__builtin_inff();

  const int koff = (wq * 16 + (lane >> 3)) * 64 + (((lane & 7) ^ (lane >> 3)) * 8);
  const int voff = (wq * 16 + (lane >> 3)) * 4096 + (((lane & 7) ^ (lane >> 3)) * 8);

  const int qrow = q0 + wq * 32 + r31;
  bf16x8 aq[4];
#pragma unroll
  for (int ks = 0; ks < 4; ++ks)
    aq[ks] = *reinterpret_cast<const bf16x8*>(Q + (size_t)qrow * 64 + ks * 16 + h * 8);

  f32x16 accO[2];
#pragma unroll
  for (int et = 0; et < 2; ++et)
#pragma unroll
    for (int i = 0; i < 16; ++i) accO[et][i] = 0.f;
  float mrow = NEG_INF, lrow = 0.f;

  gload_lds16(Kp + koff,         &sK[0][wq * 1024]);
  gload_lds16(Kp + koff + 512,   &sK[0][wq * 1024 + 512]);
  gload_lds16(Vp + voff,         &sV[0][wq * 1024]);
  gload_lds16(Vp + voff + 32768, &sV[0][wq * 1024 + 512]);
  __syncthreads();

  const int qmaxw = q0 + wq * 32 + 31;
  int buf = 0;
  for (int jt = 0; jt < ntile; ++jt) {
    if (jt < ntile - 1) {
      const hbf* Kg = Kp + (size_t)(jt + 1) * 4096;
      gload_lds16(Kg + koff,       &sK[buf ^ 1][wq * 1024]);
      gload_lds16(Kg + koff + 512, &sK[buf ^ 1][wq * 1024 + 512]);
      const hbf* Vg = Vp + (jt + 1) * 64;
      gload_lds16(Vg + voff,         &sV[buf ^ 1][wq * 1024]);
      gload_lds16(Vg + voff + 32768, &sV[buf ^ 1][wq * 1024 + 512]);
    }

    if (64 * jt <= qmaxw) {
      const __bf16* sKb = sK[buf];
      const __bf16* sVb = sV[buf];

      f32x16 accS[2];
      __builtin_amdgcn_s_setprio(1);
#pragma unroll
      for (int t = 0; t < 2; ++t) {
        f32x16 s;
#pragma unroll
        for (int i = 0; i < 16; ++i) s[i] = 0.f;
#pragma unroll
        for (int ks = 0; ks < 4; ++ks) {
          bf16x8 ak = *reinterpret_cast<const bf16x8*>(
              sKb + (t * 32 + r31) * 64 + (((2 * ks + h) ^ (r31 & 7)) * 8));
          s = __builtin_amdgcn_mfma_f32_32x32x16_bf16(ak, aq[ks], s, 0, 0, 0);
        }
        accS[t] = s;
      }
      __builtin_amdgcn_s_setprio(0);

      if (64 * jt + 63 > q0 + wq * 32) {
#pragma unroll
        for (int t = 0; t < 2; ++t)
#pragma unroll
          for (int i = 0; i < 16; ++i) {
            const int kvg = 64 * jt + 32 * t + (i & 3) + 8 * (i >> 2) + 4 * h;
            if (kvg > qrow) accS[t][i] = NEG_INF;
          }
      }

      float g0 = max3f(accS[0][0], accS[0][1], accS[0][2]);
      float g1 = max3f(accS[0][3], accS[0][4], accS[0][5]);
      float g2 = max3f(accS[0][6], accS[0][7], accS[0][8]);
      float g3 = max3f(accS[0][9], accS[0][10], accS[0][11]);
      float g4 = max3f(accS[0][12], accS[0][13], accS[0][14]);
      float g5 = max3f(accS[0][15], accS[1][0], accS[1][1]);
      float g6 = max3f(accS[1][2], accS[1][3], accS[1][4]);
      float g7 = max3f(accS[1][5], accS[1][6], accS[1][7]);
      float g8 = max3f(accS[1][8], accS[1][9], accS[1][10]);
      float g9 = max3f(accS[1][11], accS[1][12], accS[1][13]);
      float gA = fmaxf(accS[1][14], accS[1][15]);
      float h0 = max3f(g0, g1, g2);
      float h1 = max3f(g3, g4, g5);
      float h2 = max3f(g6, g7, g8);
      float h3 = fmaxf(g9, gA);
      float pmax = fmaxf(max3f(h0, h1, h2), h3);
      pmax = fmaxf(pmax, __shfl_xor(pmax, 32));

      if (!__all(pmax - mrow <= 8.f)) {
        const float mn = fmaxf(mrow, pmax);
        const float corr = __builtin_amdgcn_exp2f(mrow - mn);
        mrow = mn;
        lrow *= corr;
#pragma unroll
        for (int et = 0; et < 2; ++et)
#pragma unroll
          for (int i = 0; i < 16; ++i) accO[et][i] *= corr;
      }

#pragma unroll
      for (int t = 0; t < 2; ++t)
#pragma unroll
        for (int i = 0; i < 16; ++i)
          accS[t][i] = __builtin_amdgcn_exp2f(accS[t][i] - mrow);
      float s0 = (accS[0][0] + accS[0][1]) + (accS[0][2] + accS[0][3]);
      float s1 = (accS[0][4] + accS[0][5]) + (accS[0][6] + accS[0][7]);
      float s2 = (accS[0][8] + accS[0][9]) + (accS[0][10] + accS[0][11]);
      float s3 = (accS[0][12] + accS[0][13]) + (accS[0][14] + accS[0][15]);
      float s4 = (accS[1][0] + accS[1][1]) + (accS[1][2] + accS[1][3]);
      float s5 = (accS[1][4] + accS[1][5]) + (accS[1][6] + accS[1][7]);
      float s6 = (accS[1][8] + accS[1][9]) + (accS[1][10] + accS[1][11]);
      float s7 = (accS[1][12] + accS[1][13]) + (accS[1][14] + accS[1][15]);
      float rs = ((s0 + s1) + (s2 + s3)) + ((s4 + s5) + (s6 + s7));
      rs += __shfl_xor(rs, 32);
      lrow += rs;

      uint32_t d0[2][4], d1[2][4];
#pragma unroll
      for (int t = 0; t < 2; ++t)
#pragma unroll
        for (int r4 = 0; r4 < 4; ++r4) {
          d0[t][r4] = cvtpk(accS[t][4 * r4 + 0], accS[t][4 * r4 + 1]);
          d1[t][r4] = cvtpk(accS[t][4 * r4 + 2], accS[t][4 * r4 + 3]);
        }

#pragma unroll
      for (int kb = 0; kb < 4; ++kb) {
        const int t = kb >> 1, ra = 2 * (kb & 1), rb = ra + 1;
        uint32_t x0 = d0[t][ra], y0 = d0[t][rb];
        uint32_t x1 = d1[t][ra], y1 = d1[t][rb];
        pl32swap(x0, y0);
        pl32swap(x1, y1);
        union { uint32_t u[4]; bf16x8 v; } bP;
        bP.u[0] = x0; bP.u[1] = x1; bP.u[2] = y0; bP.u[3] = y1;
        __builtin_amdgcn_s_setprio(1);
#pragma unroll
        for (int et = 0; et < 2; ++et) {
          bf16x8 av = *reinterpret_cast<const bf16x8*>(
              sVb + (et * 32 + r31) * 64 + (((2 * kb + h) ^ (r31 & 7)) * 8));
          accO[et] = __builtin_amdgcn_mfma_f32_32x32x16_bf16(av, bP.v, accO[et], 0, 0, 0);
        }
        __builtin_amdgcn_s_setprio(0);
      }
    }

    __syncthreads();
    buf ^= 1;
  }

  const float inv = 1.0f / lrow;
  hbf* arow = attn + ((size_t)(bh >> 4) * 4096 + qrow) * 1024 + (bh & 15) * 64;
#pragma unroll
  for (int et = 0; et < 2; ++et)
#pragma unroll
    for (int r4 = 0; r4 < 4; ++r4) {
      const int e0 = et * 32 + 8 * r4 + 4 * h;
      ushort4 o;
      o.x = b2u(accO[et][4 * r4 + 0] * inv);
      o.y = b2u(accO[et][4 * r4 + 1] * inv);
      o.z = b2u(accO[et][4 * r4 + 2] * inv);
      o.w = b2u(accO[et][4 * r4 + 3] * inv);
      *reinterpret_cast<ushort4*>(arow + e0) = o;
    }
}

// ---------------- output projection GEMM (8-phase 128x256, fp32 out) ----------------
// Same schedule as k_gemm_qkv; grid (64,4) = 256 blocks = 1/CU.

__global__ __launch_bounds__(512) void k_gemm_out(
    const hbf* __restrict__ A, const hbf* __restrict__ Bw,
    const float* __restrict__ bp, float* __restrict__ out) {
  __shared__ __align__(16) hbf sA[2][128 * 64];
  __shared__ __align__(16) hbf sB[2][256 * 64];
  const int tid = threadIdx.x;
  const int lane = tid & 63, w = tid >> 6;
  const int wm = w >> 2, wn = w & 3;
  const int g = lane >> 4, cl = lane & 15;
  const int m0 = blockIdx.x * 128, n0 = blockIdx.y * 256;
  const int sr = tid >> 3, sc = tid & 7;

  const f32x4 fz = {0.f, 0.f, 0.f, 0.f};
  f32x4 acc[4][4];
#pragma unroll
  for (int a = 0; a < 4; ++a)
#pragma unroll
    for (int b = 0; b < 4; ++b) acc[a][b] = fz;

#pragma unroll
  for (int kt = 0; kt < 2; ++kt) {
#pragma unroll
    for (int s = 0; s < 2; ++s) {
      const int row = s * 64 + sr;
      gload_lds16(A + (size_t)(m0 + row) * 1024 + kt * 64 + ((sc ^ (row & 7)) * 8),
                  &sA[kt][s * 4096 + tid * 8]);
    }
#pragma unroll
    for (int s = 0; s < 4; ++s) {
      const int row = s * 64 + sr;
      gload_lds16(Bw + (size_t)(n0 + row) * 1024 + kt * 64 + ((sc ^ (row & 7)) * 8),
                  &sB[kt][s * 4096 + tid * 8]);
    }
  }
  asm volatile("s_waitcnt vmcnt(6)" ::: "memory");
  __builtin_amdgcn_s_barrier();

  for (int kt = 0; kt < 16; ++kt) {
    const int bi = kt & 1;
    const bool st = (kt + 2) < 16;

    bf16x8 af[4][2], bf[4][2];
#pragma unroll
    for (int rt = 0; rt < 4; ++rt)
#pragma unroll
      for (int ks = 0; ks < 2; ++ks)
        af[rt][ks] = *reinterpret_cast<const bf16x8*>(
            &sA[bi][(wm * 64 + rt * 16 + cl) * 64 + (((ks * 4 + g) ^ (cl & 7)) * 8)]);
#pragma unroll
    for (int ct = 0; ct < 4; ++ct)
#pragma unroll
      for (int ks = 0; ks < 2; ++ks)
        bf[ct][ks] = *reinterpret_cast<const bf16x8*>(
            &sB[bi][(wn * 64 + ct * 16 + cl) * 64 + (((ks * 4 + g) ^ (cl & 7)) * 8)]);
    __builtin_amdgcn_s_barrier();
    asm volatile("s_waitcnt lgkmcnt(0)" ::: "memory");
    __builtin_amdgcn_sched_barrier(0);
    __builtin_amdgcn_s_setprio(1);
#pragma unroll
    for (int rt = 0; rt < 4; ++rt)
#pragma unroll
      for (int ks = 0; ks < 2; ++ks)
        acc[rt][0] = __builtin_amdgcn_mfma_f32_16x16x32_bf16(af[rt][ks], bf[0][ks], acc[rt][0], 0, 0, 0);
    __builtin_amdgcn_s_setprio(0);
    __builtin_amdgcn_s_barrier();

#pragma unroll
    for (int q = 1; q < 4; ++q) {
      if (st) {
        if (q == 1) {
#pragma unroll
          for (int s = 0; s < 2; ++s) {
            const int row = s * 64 + sr;
            gload_lds16(A + (size_t)(m0 + row) * 1024 + (kt + 2) * 64 + ((sc ^ (row & 7)) * 8),
                        &sA[bi][s * 4096 + tid * 8]);
          }
        } else {
#pragma unroll
          for (int s2 = 0; s2 < 2; ++s2) {
            const int s = (q - 2) * 2 + s2;
            const int row = s * 64 + sr;
            gload_lds16(Bw + (size_t)(n0 + row) * 1024 + (kt + 2) * 64 + ((sc ^ (row & 7)) * 8),
                        &sB[bi][s * 4096 + tid * 8]);
          }
        }
      }
      __builtin_amdgcn_s_setprio(1);
#pragma unroll
      for (int rt = 0; rt < 4; ++rt)
#pragma unroll
        for (int ks = 0; ks < 2; ++ks)
          acc[rt][q] = __builtin_amdgcn_mfma_f32_16x16x32_bf16(af[rt][ks], bf[q][ks], acc[rt][q], 0, 0, 0);
      __builtin_amdgcn_s_setprio(0);
      if (q == 3) {
        if (st) asm volatile("s_waitcnt vmcnt(6)" ::: "memory");
        else    asm volatile("s_waitcnt vmcnt(0)" ::: "memory");
      }
      __builtin_amdgcn_s_barrier();
    }
  }

#pragma unroll
  for (int rt = 0; rt < 4; ++rt)
#pragma unroll
    for (int ct = 0; ct < 4; ++ct) {
      const int colg = n0 + wn * 64 + ct * 16 + cl;
      const float bi_ = bp[colg];
#pragma unroll
      for (int i = 0; i < 4; ++i) {
        const int rowg = m0 + wm * 64 + rt * 16 + g * 4 + i;
        out[(size_t)rowg * 1024 + colg] = acc[rt][ct][i] + bi_;
      }
    }
}

// ---------------- launcher ----------------

extern "C" void kernel_launch(void* const* d_in, const int* in_sizes, int n_in,
                              void* d_out, int out_size, void* d_ws, size_t ws_size,
                              hipStream_t stream) {
  const float* x  = (const float*)d_in[0];
  const float* Wq = (const float*)d_in[1];
  const float* Wk = (const float*)d_in[2];
  const float* Wv = (const float*)d_in[3];
  const float* bq = (const float*)d_in[4];
  const float* bk = (const float*)d_in[5];
  const float* bv = (const float*)d_in[6];
  const float* Wp = (const float*)d_in[7];
  const float* bp = (const float*)d_in[8];
  float* out = (float*)d_out;

  char* ws = (char*)d_ws;
  hbf*   xb    = (hbf*)ws;                                   // 16 MiB (reused as attn_out)
  hbf*   Wt    = (hbf*)(ws + 16777216);                      // 6 MiB
  hbf*   Wpt   = (hbf*)(ws + 16777216 + 6291456);            // 2 MiB
  float* biasc = (float*)(ws + 16777216 + 6291456 + 2097152);// 12 KiB (+pad)
  hbf*   qkv   = (hbf*)(ws + 16777216 + 6291456 + 2097152 + 16384); // 48 MiB
  hbf*   attn  = xb;

  k_cvt_all<<<24588, 256, 0, stream>>>(x, Wq, Wk, Wv, bq, bk, bv, Wp,
                                       xb, Wt, Wpt, biasc);

  dim3 g1(64, 12); k_gemm_qkv<<<g1, 512, 0, stream>>>(xb, Wt, biasc, qkv);
  dim3 g2(32, 32); k_flash   <<<g2, 256, 0, stream>>>(qkv, attn);
  dim3 g3(64, 4);  k_gemm_out<<<g3, 512, 0, stream>>>(attn, Wpt, bp, out);
}